// Round 12
// baseline (284.140 us; speedup 1.0000x reference)
//
#include <hip/hip_runtime.h>
#include <hip/hip_fp16.h>

#define N_NODES 100000
#define IN_DIM 256
#define OUT_DIM 64
#define NT 782                 // dst bins of 128 nodes
#define NSC 512                // scatter blocks
#define SMAX 3200              // staged edges per scatter sub-batch
#define CAP_F 3072             // per-bin capacity (mean 2048, sigma~45 -> +22 sigma)
#define GEMM_BLKS 1563         // (N_NODES+63)/64
#define NSPLIT 2               // blocks per bin in fused2 (redundant CSR build, split nodes)
#define A_LD 136
#define FUSED_LDS (64 * A_LD * 2 * 2)   // 34816 B (gemm sA+sB; scatter-D sort needs 28.6 KB)

typedef _Float16 half8 __attribute__((ext_vector_type(8)));
typedef float f32x4 __attribute__((ext_vector_type(4)));

// ---------------- pass 0: zero bin cursors + deg_out ----------------
__global__ __launch_bounds__(256) void init_kernel(int* __restrict__ cursorD,
                                                   int* __restrict__ deg_out) {
    int i = blockIdx.x * 256 + threadIdx.x;
    if (i < N_NODES) deg_out[i] = 0;
    if (i < NT) cursorD[i] = 0;
}

// ---------------- pass 1 (FUSED): scatter-D + deg_out atomics (blocks 0..511) || gemm ----------------
// r11 lesson: the counting-sort burst write-out MUST stay in the fused context
// (direct writes: WRITE 37->93MB = +9us). S-stream deleted; deg_out via global
// atomics here, hidden under gemm's ~76us (hypothesis; r3-r5 serial cost ~25-30us).
// Scatter sort LDS = 28.6 KB < gemm's 34.8 KB -> static LDS stays gemm-sized.
__global__ __launch_bounds__(256) void fused_kernel(const int* __restrict__ src,
                                                    const int* __restrict__ dst,
                                                    int* __restrict__ cursorD,
                                                    int* __restrict__ binnedD,
                                                    int* __restrict__ deg_out,
                                                    const float* __restrict__ hmat,
                                                    const float* __restrict__ W,
                                                    __half* __restrict__ xh,
                                                    int E, int chunk) {
    __shared__ char smem[FUSED_LDS];
    const int t = threadIdx.x;
    if (blockIdx.x < NSC) {
        // ================= scatter body (D-stream counting-sort, r9-proven) =================
        int* sorted          = (int*)(smem);                    // 12800 B
        unsigned short* sbin = (unsigned short*)(smem + 12800); // 6400 B
        int* histD           = (int*)(smem + 19200);            // 3128 B
        int* boffD           = (int*)(smem + 22328);            // 3128 B
        int* resvD           = (int*)(smem + 25456);            // 3128 B -> 28584
        const int blk = blockIdx.x;
        const int lane = t & 63, wv = t >> 6;
        const int lo = blk * chunk;
        int hiA = lo + chunk; if (hiA > E) hiA = E;
        for (int s0 = lo; s0 < hiA; s0 += SMAX) {
            int m = hiA - s0; if (m > SMAX) m = SMAX;
            for (int i = t; i < NT; i += 256) histD[i] = 0;
            __syncthreads();
            // A: histogram dst bins + deg_out atomics (fire-and-forget, overlapped w/ gemm)
            for (int k = t; k < m; k += 256) {
                atomicAdd(&deg_out[src[s0 + k]], 1);
                atomicAdd(&histD[dst[s0 + k] >> 7], 1);
            }
            __syncthreads();
            // B1: 1-wave exclusive scan -> boffD
            if (wv == 0) {
                int carry = 0;
                for (int r = 0; r < (NT + 63) / 64; ++r) {
                    int i = r * 64 + lane;
                    int v = (i < NT) ? histD[i] : 0;
                    int incl = v;
#pragma unroll
                    for (int off = 1; off < 64; off <<= 1) {
                        int y = __shfl_up(incl, off);
                        if (lane >= off) incl += y;
                    }
                    if (i < NT) boffD[i] = carry + incl - v;
                    carry += __shfl(incl, 63);
                }
            }
            __syncthreads();
            // B2: reserve contiguous global ranges; hist becomes place cursor
            for (int i = t; i < NT; i += 256) {
                int hd = histD[i];
                if (hd) resvD[i] = atomicAdd(&cursorD[i], hd);
                histD[i] = boffD[i];
            }
            __syncthreads();
            // C: re-read (L2-hot) and counting-sort into LDS
            for (int k = t; k < m; k += 256) {
                int s = src[s0 + k], d = dst[s0 + k];
                int bd = d >> 7;
                int p = atomicAdd(&histD[bd], 1);
                sorted[p] = (s << 7) | (d & 127);
                sbin[p] = (unsigned short)bd;
            }
            __syncthreads();
            // D: burst write-out — consecutive k => consecutive addresses within a bin run
            for (int k = t; k < m; k += 256) {
                int b = sbin[k];
                int loc = resvD[b] + (k - boffD[b]);
                if (loc < CAP_F) binnedD[b * CAP_F + loc] = sorted[k];
            }
            __syncthreads();
        }
    } else {
        // ================= gemm body (UNSCALED; norm applied in fused2) =================
        _Float16* sA = (_Float16*)(smem);                   // 17408 B
        _Float16* sB = (_Float16*)(smem + 64 * A_LD * 2);   // 17408 B
        const int lane = t & 63;
        const int w = t >> 6;
        const int row0 = (blockIdx.x - NSC) * 64;
        const int m0 = (w & 1) * 32;
        const int n0 = (w >> 1) * 32;

        f32x4 acc00 = {0.f, 0.f, 0.f, 0.f}, acc01 = {0.f, 0.f, 0.f, 0.f};
        f32x4 acc10 = {0.f, 0.f, 0.f, 0.f}, acc11 = {0.f, 0.f, 0.f, 0.f};

        for (int khalf = 0; khalf < 2; ++khalf) {
            const int k0 = khalf * 128;
            __syncthreads();
#pragma unroll
            for (int it = 0; it < 8; ++it) {
                int f = t + it * 256;
                int row = f >> 5;
                int c4 = f & 31;
                int grow = row0 + row; if (grow >= N_NODES) grow = N_NODES - 1;
                float4 v = *(const float4*)(hmat + (size_t)grow * IN_DIM + k0 + c4 * 4);
                _Float16 p[4];
                p[0] = (_Float16)v.x; p[1] = (_Float16)v.y;
                p[2] = (_Float16)v.z; p[3] = (_Float16)v.w;
                *(uint2*)&sA[row * A_LD + c4 * 4] = *(uint2*)p;
            }
            {
                int n = t & 63;
                int kk0 = (t >> 6) * 32;
#pragma unroll
                for (int kb = 0; kb < 8; ++kb) {
                    _Float16 p[4];
#pragma unroll
                    for (int u = 0; u < 4; ++u)
                        p[u] = (_Float16)W[(size_t)(k0 + kk0 + kb * 4 + u) * OUT_DIM + n];
                    *(uint2*)&sB[n * A_LD + kk0 + kb * 4] = *(uint2*)p;
                }
            }
            __syncthreads();
#pragma unroll
            for (int kb = 0; kb < 4; ++kb) {
                int koff = kb * 32 + (lane >> 4) * 8;
                half8 a0 = *(const half8*)&sA[(m0 + (lane & 15)) * A_LD + koff];
                half8 a1 = *(const half8*)&sA[(m0 + 16 + (lane & 15)) * A_LD + koff];
                half8 b0 = *(const half8*)&sB[(n0 + (lane & 15)) * A_LD + koff];
                half8 b1 = *(const half8*)&sB[(n0 + 16 + (lane & 15)) * A_LD + koff];
                acc00 = __builtin_amdgcn_mfma_f32_16x16x32_f16(a0, b0, acc00, 0, 0, 0);
                acc01 = __builtin_amdgcn_mfma_f32_16x16x32_f16(a0, b1, acc01, 0, 0, 0);
                acc10 = __builtin_amdgcn_mfma_f32_16x16x32_f16(a1, b0, acc10, 0, 0, 0);
                acc11 = __builtin_amdgcn_mfma_f32_16x16x32_f16(a1, b1, acc11, 0, 0, 0);
            }
        }

        const int col16 = lane & 15;
        const int rq = (lane >> 4) * 4;
#pragma unroll
        for (int mi = 0; mi < 2; ++mi) {
#pragma unroll
            for (int ni = 0; ni < 2; ++ni) {
                const f32x4 a = (mi == 0) ? (ni == 0 ? acc00 : acc01)
                                          : (ni == 0 ? acc10 : acc11);
                int col = n0 + ni * 16 + col16;
#pragma unroll
                for (int r = 0; r < 4; ++r) {
                    int row = row0 + m0 + mi * 16 + rq + r;
                    if (row < N_NODES)
                        xh[(size_t)row * OUT_DIM + col] = __float2half(a[r]);
                }
            }
        }
    }
}

// ---------------- pass 2 (FUSED tile+aggregate): per-(bin,half) block ----------------
// Build the bin's CSR in LDS (lcsr never touches global — deletes 12.8 MB csr traffic
// and the tile launch), then aggregate this block's 64 nodes straight from LDS.
// NSPLIT=2 blocks redundantly build the same bin's CSR (cheap: 2048 reads + LDS atomics)
// -> 1564 blocks, ~6/CU, 24 waves/CU for gather latency hiding.
// Per-edge weight = rsqrt(deg_out[s]) loaded on the fly (broadcast across 8 lanes).
__global__ __launch_bounds__(256) void agg_kernel(const int* __restrict__ cursorD,
                                                  const int* __restrict__ binnedD,
                                                  const int* __restrict__ deg_out,
                                                  const __half* __restrict__ xh,
                                                  const float* __restrict__ b,
                                                  float* __restrict__ out) {
    __shared__ int lcsr[CAP_F];                       // 12288 B
    __shared__ int h[128], cur[128], loff[128], lcnt[128];
    __shared__ int w0tot;
    const int bin = blockIdx.x / NSPLIT;
    const int half = blockIdx.x % NSPLIT;
    const int t = threadIdx.x, lane = t & 63, wv = t >> 6;

    // ---- CSR build (tile dst-phase, output kept in LDS) ----
    if (t < 128) h[t] = 0;
    __syncthreads();
    const int base = bin * CAP_F;
    int m = cursorD[bin]; if (m > CAP_F) m = CAP_F;
    for (int k = t; k < m; k += 256) atomicAdd(&h[binnedD[base + k] & 127], 1);
    __syncthreads();
    int v = (t < 128) ? h[t] : 0;
    int incl = v;
#pragma unroll
    for (int off = 1; off < 64; off <<= 1) {
        int y = __shfl_up(incl, off);
        if (lane >= off) incl += y;
    }
    if (t == 63) w0tot = incl;
    __syncthreads();
    int excl = incl - v + ((t >= 64 && t < 128) ? w0tot : 0);
    if (t < 128) { loff[t] = excl; lcnt[t] = v; cur[t] = excl; }
    __syncthreads();
    for (int k = t; k < m; k += 256) {
        int rec = binnedD[base + k];
        int p = atomicAdd(&cur[rec & 127], 1);
        lcsr[p] = rec >> 7;
    }
    __syncthreads();

    // ---- aggregate this block's 64 nodes (16 per wave, sequential) ----
    const int g = lane >> 3;
    const int c = lane & 7;
    for (int idx = 0; idx < 16; ++idx) {
        const int nloc = half * 64 + wv * 16 + idx;
        const int node = bin * 128 + nloc;
        if (node >= N_NODES) continue;
        const int start = loff[nloc];
        const int n = lcnt[nloc];

        float acc[8] = {0.f, 0.f, 0.f, 0.f, 0.f, 0.f, 0.f, 0.f};
        for (int bb = 0; bb < n; bb += 64) {
            int k = bb + lane;
            int sidx = (k < n) ? lcsr[start + k] : 0;
            int mm = n - bb; if (mm > 64) mm = 64;
            for (int e0 = 0; e0 < mm; e0 += 16) {
                int ea = e0 + g;
                int eb = e0 + 8 + g;
                int sa = __shfl(sidx, ea);
                int sb = __shfl(sidx, eb);
                bool va = ea < mm;
                bool vb = eb < mm;
                int sa0 = va ? sa : 0;
                int dga = deg_out[sa0];
                float wa = va ? rsqrtf((float)(dga < 1 ? 1 : dga)) : 0.f;
                uint4 ra = *(const uint4*)(xh + (size_t)sa0 * OUT_DIM + 8 * c);
                const bool grpb = (e0 + 8) < mm;  // wave-uniform
                uint4 rb;
                float wb = 0.f;
                if (grpb) {
                    int sb0 = vb ? sb : 0;
                    int dgb = deg_out[sb0];
                    wb = vb ? rsqrtf((float)(dgb < 1 ? 1 : dgb)) : 0.f;
                    rb = *(const uint4*)(xh + (size_t)sb0 * OUT_DIM + 8 * c);
                }
                {
                    const __half2* hp = (const __half2*)&ra;
#pragma unroll
                    for (int p = 0; p < 4; ++p) {
                        float2 f = __half22float2(hp[p]);
                        acc[2 * p]     = fmaf(wa, f.x, acc[2 * p]);
                        acc[2 * p + 1] = fmaf(wa, f.y, acc[2 * p + 1]);
                    }
                }
                if (grpb) {
                    const __half2* hp = (const __half2*)&rb;
#pragma unroll
                    for (int p = 0; p < 4; ++p) {
                        float2 f = __half22float2(hp[p]);
                        acc[2 * p]     = fmaf(wb, f.x, acc[2 * p]);
                        acc[2 * p + 1] = fmaf(wb, f.y, acc[2 * p + 1]);
                    }
                }
            }
        }

        // reduce over the 8 edge groups
#pragma unroll
        for (int off = 8; off < 64; off <<= 1) {
#pragma unroll
            for (int p = 0; p < 8; ++p)
                acc[p] += __shfl_xor(acc[p], off);
        }

        if (g == 0) {
            float nrm = rsqrtf((float)(n < 1 ? 1 : n));
            float4 bv0 = *(const float4*)&b[c * 8];
            float4 bv1 = *(const float4*)&b[c * 8 + 4];
            float4 r0, r1;
            r0.x = fmaxf(fmaf(acc[0], nrm, bv0.x), 0.f);
            r0.y = fmaxf(fmaf(acc[1], nrm, bv0.y), 0.f);
            r0.z = fmaxf(fmaf(acc[2], nrm, bv0.z), 0.f);
            r0.w = fmaxf(fmaf(acc[3], nrm, bv0.w), 0.f);
            r1.x = fmaxf(fmaf(acc[4], nrm, bv1.x), 0.f);
            r1.y = fmaxf(fmaf(acc[5], nrm, bv1.y), 0.f);
            r1.z = fmaxf(fmaf(acc[6], nrm, bv1.z), 0.f);
            r1.w = fmaxf(fmaf(acc[7], nrm, bv1.w), 0.f);
            float4* orow = (float4*)(out + (size_t)node * OUT_DIM + c * 8);
            orow[0] = r0;
            orow[1] = r1;
        }
    }
}

extern "C" void kernel_launch(void* const* d_in, const int* in_sizes, int n_in,
                              void* d_out, int out_size, void* d_ws, size_t ws_size,
                              hipStream_t stream) {
    const float* h   = (const float*)d_in[0];
    const int*   src = (const int*)d_in[1];
    const int*   dst = (const int*)d_in[2];
    const float* W   = (const float*)d_in[3];
    const float* b   = (const float*)d_in[4];
    float* out = (float*)d_out;
    const int E = in_sizes[1];
    const int chunkS = (E + NSC - 1) / NSC;

    // workspace layout (16B aligned); everything written before read. ~22.8 MB.
    char* ws = (char*)d_ws;
    int*    cursorD = (int*)(ws);                    // NT ints (pad 3328 B)
    int*    deg_out = (int*)(ws + 3328);             // N ints (400,000 B)
    int*    binnedD = (int*)(ws + 403328);           // NT*CAP_F ints (9.61 MB)
    __half* xh      = (__half*)(ws + 10012544);      // N*64 halfs (12.8 MB)

    init_kernel<<<(N_NODES + 255) / 256, 256, 0, stream>>>(cursorD, deg_out);
    fused_kernel<<<NSC + GEMM_BLKS, 256, 0, stream>>>(src, dst, cursorD, binnedD, deg_out,
                                                      h, W, xh, E, chunkS);
    agg_kernel<<<NT * NSPLIT, 256, 0, stream>>>(cursorD, binnedD, deg_out, xh, b, out);
}

// Round 13
// 252.506 us; speedup vs baseline: 1.1253x; 1.1253x over previous
//
#include <hip/hip_runtime.h>
#include <hip/hip_fp16.h>

#define N_NODES 100000
#define IN_DIM 256
#define OUT_DIM 64
#define NT 782                 // bins of 128 nodes (dst bins and src bins)
#define NSC 512                // scatter blocks
#define SMAX 3200              // staged edges per scatter sub-batch
#define CAP_F 3072             // per-bin capacity (mean 2048, sigma~45 -> +22 sigma)
#define GEMM_BLKS 1563         // (N_NODES+63)/64
#define NSPLIT 4               // blocks per bin in agg (redundant CSR build, split nodes)
#define A_LD 136
#define FUSED_LDS 47568        // r9-proven overlay: scatter dual-stream sort / gemm sA+sB

typedef _Float16 half8 __attribute__((ext_vector_type(8)));
typedef float f32x4 __attribute__((ext_vector_type(4)));

// ---------------- pass 0: zero bin cursors ----------------
__global__ __launch_bounds__(256) void init_kernel(int* __restrict__ cursorD,
                                                   int* __restrict__ cursorS) {
    int i = blockIdx.x * 256 + threadIdx.x;
    if (i < NT) { cursorD[i] = 0; cursorS[i] = 0; }
}

// ---------------- pass 1 (FUSED): r9-exact dual-binned scatter || unscaled gemm ----------------
// NO per-edge global atomics (r12 falsifier: they cost ~28us even "hidden" under gemm —
// they serialize in the L2 atomic path). deg_out comes from the srcb byte stream (scale
// pass). Counting-sort burst write-out kept (r11: direct writes +56MB WRITE = +9us).
__global__ __launch_bounds__(256) void fused_kernel(const int* __restrict__ src,
                                                    const int* __restrict__ dst,
                                                    int* __restrict__ cursorD,
                                                    int* __restrict__ cursorS,
                                                    int* __restrict__ binnedD,
                                                    unsigned char* __restrict__ srcb,
                                                    const float* __restrict__ hmat,
                                                    const float* __restrict__ W,
                                                    __half* __restrict__ xh,
                                                    int E, int chunk) {
    __shared__ char smem[FUSED_LDS];
    const int t = threadIdx.x;
    if (blockIdx.x < NSC) {
        // ================= scatter body (r9-exact) =================
        int* sorted            = (int*)(smem);                    // 12800 B
        int* histD             = (int*)(smem + 12800);            // 3128 B
        int* boffD             = (int*)(smem + 15928);
        int* resvD             = (int*)(smem + 19056);
        int* histS             = (int*)(smem + 22184);
        int* boffS             = (int*)(smem + 25312);
        int* resvS             = (int*)(smem + 28440);            // ends 31568
        unsigned short* sbin   = (unsigned short*)(smem + 31568); // 6400 B
        unsigned short* sbinS  = (unsigned short*)(smem + 37968); // 6400 B
        unsigned char* sortedB = (unsigned char*)(smem + 44368);  // 3200 B -> 47568
        const int blk = blockIdx.x;
        const int lane = t & 63, wv = t >> 6;
        const int lo = blk * chunk;
        int hiA = lo + chunk; if (hiA > E) hiA = E;
        for (int s0 = lo; s0 < hiA; s0 += SMAX) {
            int m = hiA - s0; if (m > SMAX) m = SMAX;
            for (int i = t; i < NT; i += 256) { histD[i] = 0; histS[i] = 0; }
            __syncthreads();
            // A: dual histogram (coalesced edge reads, LDS atomics only)
            for (int k = t; k < m; k += 256) {
                int s = src[s0 + k], d = dst[s0 + k];
                atomicAdd(&histD[d >> 7], 1);
                atomicAdd(&histS[s >> 7], 1);
            }
            __syncthreads();
            // B1: two 1-wave exclusive scans (wave0: dst, wave1: src)
            if (wv < 2) {
                int* hsrc = (wv == 0) ? histD : histS;
                int* bdst = (wv == 0) ? boffD : boffS;
                int carry = 0;
                for (int r = 0; r < (NT + 63) / 64; ++r) {
                    int i = r * 64 + lane;
                    int v = (i < NT) ? hsrc[i] : 0;
                    int incl = v;
#pragma unroll
                    for (int off = 1; off < 64; off <<= 1) {
                        int y = __shfl_up(incl, off);
                        if (lane >= off) incl += y;
                    }
                    if (i < NT) bdst[i] = carry + incl - v;
                    carry += __shfl(incl, 63);
                }
            }
            __syncthreads();
            // B2: reserve contiguous global ranges; hist becomes place cursor
            for (int i = t; i < NT; i += 256) {
                int hd = histD[i];
                if (hd) resvD[i] = atomicAdd(&cursorD[i], hd);
                int hs = histS[i];
                if (hs) resvS[i] = atomicAdd(&cursorS[i], hs);
                histD[i] = boffD[i];
                histS[i] = boffS[i];
            }
            __syncthreads();
            // C: re-read (L2-hot) and counting-sort both streams into LDS
            for (int k = t; k < m; k += 256) {
                int s = src[s0 + k], d = dst[s0 + k];
                int bd = d >> 7;
                int p = atomicAdd(&histD[bd], 1);
                sorted[p] = (s << 7) | (d & 127);
                sbin[p] = (unsigned short)bd;
                int bs = s >> 7;
                int ps = atomicAdd(&histS[bs], 1);
                sortedB[ps] = (unsigned char)(s & 127);
                sbinS[ps] = (unsigned short)bs;
            }
            __syncthreads();
            // D: burst write-out
            for (int k = t; k < m; k += 256) {
                int b = sbin[k];
                int loc = resvD[b] + (k - boffD[b]);
                if (loc < CAP_F) binnedD[b * CAP_F + loc] = sorted[k];
                int bs = sbinS[k];
                int locS = resvS[bs] + (k - boffS[bs]);
                if (locS < CAP_F) srcb[bs * CAP_F + locS] = sortedB[k];
            }
            __syncthreads();
        }
    } else {
        // ================= gemm body (UNSCALED; scale pass applies norm_src) ==========
        _Float16* sA = (_Float16*)(smem);                   // 17408 B
        _Float16* sB = (_Float16*)(smem + 64 * A_LD * 2);   // 17408 B
        const int lane = t & 63;
        const int w = t >> 6;
        const int row0 = (blockIdx.x - NSC) * 64;
        const int m0 = (w & 1) * 32;
        const int n0 = (w >> 1) * 32;

        f32x4 acc00 = {0.f, 0.f, 0.f, 0.f}, acc01 = {0.f, 0.f, 0.f, 0.f};
        f32x4 acc10 = {0.f, 0.f, 0.f, 0.f}, acc11 = {0.f, 0.f, 0.f, 0.f};

        for (int khalf = 0; khalf < 2; ++khalf) {
            const int k0 = khalf * 128;
            __syncthreads();
#pragma unroll
            for (int it = 0; it < 8; ++it) {
                int f = t + it * 256;
                int row = f >> 5;
                int c4 = f & 31;
                int grow = row0 + row; if (grow >= N_NODES) grow = N_NODES - 1;
                float4 v = *(const float4*)(hmat + (size_t)grow * IN_DIM + k0 + c4 * 4);
                _Float16 p[4];
                p[0] = (_Float16)v.x; p[1] = (_Float16)v.y;
                p[2] = (_Float16)v.z; p[3] = (_Float16)v.w;
                *(uint2*)&sA[row * A_LD + c4 * 4] = *(uint2*)p;
            }
            {
                int n = t & 63;
                int kk0 = (t >> 6) * 32;
#pragma unroll
                for (int kb = 0; kb < 8; ++kb) {
                    _Float16 p[4];
#pragma unroll
                    for (int u = 0; u < 4; ++u)
                        p[u] = (_Float16)W[(size_t)(k0 + kk0 + kb * 4 + u) * OUT_DIM + n];
                    *(uint2*)&sB[n * A_LD + kk0 + kb * 4] = *(uint2*)p;
                }
            }
            __syncthreads();
#pragma unroll
            for (int kb = 0; kb < 4; ++kb) {
                int koff = kb * 32 + (lane >> 4) * 8;
                half8 a0 = *(const half8*)&sA[(m0 + (lane & 15)) * A_LD + koff];
                half8 a1 = *(const half8*)&sA[(m0 + 16 + (lane & 15)) * A_LD + koff];
                half8 b0 = *(const half8*)&sB[(n0 + (lane & 15)) * A_LD + koff];
                half8 b1 = *(const half8*)&sB[(n0 + 16 + (lane & 15)) * A_LD + koff];
                acc00 = __builtin_amdgcn_mfma_f32_16x16x32_f16(a0, b0, acc00, 0, 0, 0);
                acc01 = __builtin_amdgcn_mfma_f32_16x16x32_f16(a0, b1, acc01, 0, 0, 0);
                acc10 = __builtin_amdgcn_mfma_f32_16x16x32_f16(a1, b0, acc10, 0, 0, 0);
                acc11 = __builtin_amdgcn_mfma_f32_16x16x32_f16(a1, b1, acc11, 0, 0, 0);
            }
        }

        const int col16 = lane & 15;
        const int rq = (lane >> 4) * 4;
#pragma unroll
        for (int mi = 0; mi < 2; ++mi) {
#pragma unroll
            for (int ni = 0; ni < 2; ++ni) {
                const f32x4 a = (mi == 0) ? (ni == 0 ? acc00 : acc01)
                                          : (ni == 0 ? acc10 : acc11);
                int col = n0 + ni * 16 + col16;
#pragma unroll
                for (int r = 0; r < 4; ++r) {
                    int row = row0 + m0 + mi * 16 + rq + r;
                    if (row < N_NODES)
                        xh[(size_t)row * OUT_DIM + col] = __float2half(a[r]);
                }
            }
        }
    }
}

// ---------------- pass 2: scale — srcb histogram -> deg -> scale xh rows in place ----------------
// Reproduces the r0-r7 epilogue numerics (xh = fp16(x * rsqrt(deg))), deleting the
// per-edge nrmS gather from agg. 12.8 MB r+w coalesced.
__global__ __launch_bounds__(256) void scale_kernel(const int* __restrict__ cursorS,
                                                    const unsigned char* __restrict__ srcb,
                                                    __half* __restrict__ xh) {
    __shared__ int h[128];
    __shared__ float sc[128];
    const int bin = blockIdx.x, t = threadIdx.x;
    if (t < 128) h[t] = 0;
    __syncthreads();
    int ms = cursorS[bin]; if (ms > CAP_F) ms = CAP_F;
    const int sbase = bin * CAP_F;
    for (int k = t; k < ms; k += 256) atomicAdd(&h[srcb[sbase + k]], 1);
    __syncthreads();
    if (t < 128) {
        int d = h[t];
        sc[t] = rsqrtf((float)(d < 1 ? 1 : d));
    }
    __syncthreads();
    const int node0 = bin * 128;
    for (int i = t; i < 128 * 16; i += 256) {   // 16 x 8B segments per 128B row
        int r = i >> 4, q = i & 15;
        int node = node0 + r;
        if (node < N_NODES) {
            __half2* p = (__half2*)(xh + (size_t)node * OUT_DIM + q * 4);
            float s = sc[r];
            __half2 a0 = p[0], a1 = p[1];
            float2 f0 = __half22float2(a0), f1 = __half22float2(a1);
            __half2 r0, r1;
            r0.x = __float2half(f0.x * s); r0.y = __float2half(f0.y * s);
            r1.x = __float2half(f1.x * s); r1.y = __float2half(f1.y * s);
            p[0] = r0; p[1] = r1;
        }
    }
}

// ---------------- pass 3: agg — CSR in LDS, pre-scaled gathers, NSPLIT=4 ----------------
// NSPLIT blocks per bin redundantly build the bin's CSR in LDS (cheap), each aggregates
// 32 nodes (8 per wave). Edge indices read straight from lcsr (no shuffles). 3128
// blocks ~ 12/CU for gather-latency TLP (r12's 6/CU was grid-limited vs ~11 LDS cap).
__global__ __launch_bounds__(256) void agg_kernel(const int* __restrict__ cursorD,
                                                  const int* __restrict__ binnedD,
                                                  const __half* __restrict__ xh,
                                                  const float* __restrict__ b,
                                                  float* __restrict__ out) {
    __shared__ int lcsr[CAP_F];                       // 12288 B
    __shared__ int h[128], cur[128], loff[128], lcnt[128];
    __shared__ int w0tot;
    const int bin = blockIdx.x / NSPLIT;
    const int part = blockIdx.x % NSPLIT;
    const int t = threadIdx.x, lane = t & 63, wv = t >> 6;

    // ---- CSR build (kept entirely in LDS) ----
    if (t < 128) h[t] = 0;
    __syncthreads();
    const int base = bin * CAP_F;
    int m = cursorD[bin]; if (m > CAP_F) m = CAP_F;
    for (int k = t; k < m; k += 256) atomicAdd(&h[binnedD[base + k] & 127], 1);
    __syncthreads();
    int v = (t < 128) ? h[t] : 0;
    int incl = v;
#pragma unroll
    for (int off = 1; off < 64; off <<= 1) {
        int y = __shfl_up(incl, off);
        if (lane >= off) incl += y;
    }
    if (t == 63) w0tot = incl;
    __syncthreads();
    int excl = incl - v + ((t >= 64 && t < 128) ? w0tot : 0);
    if (t < 128) { loff[t] = excl; lcnt[t] = v; cur[t] = excl; }
    __syncthreads();
    for (int k = t; k < m; k += 256) {
        int rec = binnedD[base + k];
        int p = atomicAdd(&cur[rec & 127], 1);
        lcsr[p] = rec >> 7;
    }
    __syncthreads();

    // ---- aggregate this block's 32 nodes (8 per wave, sequential) ----
    const int g = lane >> 3;
    const int c = lane & 7;
    for (int idx = 0; idx < 8; ++idx) {
        const int nloc = part * 32 + wv * 8 + idx;
        const int node = bin * 128 + nloc;
        if (node >= N_NODES) continue;
        const int start = loff[nloc];
        const int n = lcnt[nloc];

        float acc[8] = {0.f, 0.f, 0.f, 0.f, 0.f, 0.f, 0.f, 0.f};
        for (int e0 = 0; e0 < n; e0 += 16) {
            int ea = e0 + g;
            int eb = ea + 8;
            bool va = ea < n;
            bool vb = eb < n;
            int sa0 = va ? lcsr[start + ea] : 0;
            float wa = va ? 1.f : 0.f;
            uint4 ra = *(const uint4*)(xh + (size_t)sa0 * OUT_DIM + 8 * c);
            const bool grpb = (e0 + 8) < n;  // wave-uniform (n per-node, node per-wave)
            uint4 rb;
            float wb = 0.f;
            if (grpb) {
                int sb0 = vb ? lcsr[start + eb] : 0;
                wb = vb ? 1.f : 0.f;
                rb = *(const uint4*)(xh + (size_t)sb0 * OUT_DIM + 8 * c);
            }
            {
                const __half2* hp = (const __half2*)&ra;
#pragma unroll
                for (int p = 0; p < 4; ++p) {
                    float2 f = __half22float2(hp[p]);
                    acc[2 * p]     = fmaf(wa, f.x, acc[2 * p]);
                    acc[2 * p + 1] = fmaf(wa, f.y, acc[2 * p + 1]);
                }
            }
            if (grpb) {
                const __half2* hp = (const __half2*)&rb;
#pragma unroll
                for (int p = 0; p < 4; ++p) {
                    float2 f = __half22float2(hp[p]);
                    acc[2 * p]     = fmaf(wb, f.x, acc[2 * p]);
                    acc[2 * p + 1] = fmaf(wb, f.y, acc[2 * p + 1]);
                }
            }
        }

        // reduce over the 8 edge groups
#pragma unroll
        for (int off = 8; off < 64; off <<= 1) {
#pragma unroll
            for (int p = 0; p < 8; ++p)
                acc[p] += __shfl_xor(acc[p], off);
        }

        if (g == 0) {
            float nrm = rsqrtf((float)(n < 1 ? 1 : n));
            float4 bv0 = *(const float4*)&b[c * 8];
            float4 bv1 = *(const float4*)&b[c * 8 + 4];
            float4 r0, r1;
            r0.x = fmaxf(fmaf(acc[0], nrm, bv0.x), 0.f);
            r0.y = fmaxf(fmaf(acc[1], nrm, bv0.y), 0.f);
            r0.z = fmaxf(fmaf(acc[2], nrm, bv0.z), 0.f);
            r0.w = fmaxf(fmaf(acc[3], nrm, bv0.w), 0.f);
            r1.x = fmaxf(fmaf(acc[4], nrm, bv1.x), 0.f);
            r1.y = fmaxf(fmaf(acc[5], nrm, bv1.y), 0.f);
            r1.z = fmaxf(fmaf(acc[6], nrm, bv1.z), 0.f);
            r1.w = fmaxf(fmaf(acc[7], nrm, bv1.w), 0.f);
            float4* orow = (float4*)(out + (size_t)node * OUT_DIM + c * 8);
            orow[0] = r0;
            orow[1] = r1;
        }
    }
}

extern "C" void kernel_launch(void* const* d_in, const int* in_sizes, int n_in,
                              void* d_out, int out_size, void* d_ws, size_t ws_size,
                              hipStream_t stream) {
    const float* h   = (const float*)d_in[0];
    const int*   src = (const int*)d_in[1];
    const int*   dst = (const int*)d_in[2];
    const float* W   = (const float*)d_in[3];
    const float* b   = (const float*)d_in[4];
    float* out = (float*)d_out;
    const int E = in_sizes[1];
    const int chunkS = (E + NSC - 1) / NSC;

    // workspace layout (16B aligned); everything written before read. ~24.8 MB.
    char* ws = (char*)d_ws;
    int*           cursorD = (int*)(ws);                      // NT ints (pad 3328 B)
    int*           cursorS = (int*)(ws + 3328);               // NT ints (pad 3328 B)
    int*           binnedD = (int*)(ws + 6656);               // NT*CAP_F ints (9.61 MB)
    unsigned char* srcb    = (unsigned char*)(ws + 9615872);  // NT*CAP_F bytes (2.4 MB)
    __half*        xh      = (__half*)(ws + 12018176);        // N*64 halfs (12.8 MB)

    init_kernel<<<4, 256, 0, stream>>>(cursorD, cursorS);
    fused_kernel<<<NSC + GEMM_BLKS, 256, 0, stream>>>(src, dst, cursorD, cursorS,
                                                      binnedD, srcb, h, W, xh, E, chunkS);
    scale_kernel<<<NT, 256, 0, stream>>>(cursorS, srcb, xh);
    agg_kernel<<<NT * NSPLIT, 256, 0, stream>>>(cursorD, binnedD, xh, b, out);
}